// Round 3
// baseline (59.038 us; speedup 1.0000x reference)
//
#include <hip/hip_runtime.h>
#include <math.h>

#define EPSN 1e-12f
#define MAGIC 0x5A17C0DEu

typedef __attribute__((ext_vector_type(8))) __bf16 bf16x8;
typedef __attribute__((ext_vector_type(8))) short short8;
typedef __attribute__((ext_vector_type(4))) float floatx4;

static __device__ __forceinline__ unsigned short f2bf(float f) {
    return __builtin_bit_cast(unsigned short, (__bf16)f);
}

// ---------------------------------------------------------------------------
// Fused kernel. 256 blocks x 512 threads.
//  - blocks 0..15 first produce At[e][m][n] = bf16(A[e][n][m]/||col||) (d_ws),
//    publish via agent-scope release flag.
//  - all blocks: phase 1: XW[e][r=(bc,o)][n] = x@W -> LDS bf16, XOR-swizzled.
//  - gate: spin on 16 flags (hidden under phase-1 latency).
//  - phase 2: wave (e, m-half): out = relu(XW_e . At_e^T) via
//    mfma_f32_16x16x32_bf16, coalesced float4 stores.
// ---------------------------------------------------------------------------
__global__ __launch_bounds__(512, 2)
void gcn_fused_kernel(const float* __restrict__ x, const float* __restrict__ A,
                      const float* __restrict__ W,
                      unsigned short* __restrict__ At, unsigned* __restrict__ flags,
                      float* __restrict__ out) {
    __shared__ __align__(16) unsigned char smem[32768];  // union: prep Asub / xw
    __shared__ float red[16][32];
    __shared__ float rnv[32];

    const int t   = threadIdx.x;   // 0..511
    const int bid = blockIdx.x;    // 0..255

    // ================= prep (blocks 0..15) =================
    if (bid < 16) {
        float (*Asub)[33] = (float(*)[33])smem;   // [128 n][32 m + pad]
        const int ep = bid >> 2;
        const int m0 = (bid & 3) * 32;
        const float* Ae = A + ep * 16384 + m0;
        #pragma unroll
        for (int i = 0; i < 8; ++i) {
            int idx = i * 512 + t;               // 0..4095
            int n = idx >> 5, ml = idx & 31;
            Asub[n][ml] = Ae[n * 128 + ml];      // coalesced in m
        }
        __syncthreads();
        {
            int g = t >> 5, ml = t & 31;         // g 0..15
            float s = 0.f;
            #pragma unroll
            for (int j = 0; j < 8; ++j) {
                float v = Asub[g * 8 + j][ml];
                s += v * v;
            }
            red[g][ml] = s;
        }
        __syncthreads();
        if (t < 32) {
            float s = 0.f;
            #pragma unroll
            for (int g = 0; g < 16; ++g) s += red[g][t];
            rnv[t] = 1.0f / fmaxf(sqrtf(s), EPSN);
        }
        __syncthreads();
        {
            int ml = t >> 4;                     // 0..31
            int n0 = (t & 15) * 8;
            float r = rnv[ml];
            unsigned short hs[8];
            #pragma unroll
            for (int j = 0; j < 8; ++j)
                hs[j] = f2bf(Asub[n0 + j][ml] * r);
            *(uint4*)(At + ((size_t)(ep * 128 + m0 + ml) * 128 + n0)) =
                *(const uint4*)hs;
        }
        __threadfence();
        __syncthreads();
        if (t == 0)
            __hip_atomic_store(&flags[bid], MAGIC, __ATOMIC_RELEASE,
                               __HIP_MEMORY_SCOPE_AGENT);
        __syncthreads();   // before smem reuse as xw
    }

    // ================= phase 1: XW -> LDS =================
    const int bc0  = bid * 8;
    const int bclA = t >> 7;        // 0..3
    const int nn   = t & 127;

    float4 xf[2][4];
    {
        const float4* xp0 = (const float4*)(x + ((size_t)(bc0 + bclA) * 128 + nn) * 16);
        const float4* xp1 = (const float4*)(x + ((size_t)(bc0 + 4 + bclA) * 128 + nn) * 16);
        #pragma unroll
        for (int q = 0; q < 4; ++q) { xf[0][q] = xp0[q]; xf[1][q] = xp1[q]; }
    }

    #pragma unroll 1
    for (int e = 0; e < 4; ++e) {
        float4 We[16];
        const float4* wp = (const float4*)(W + e * 64);
        #pragma unroll
        for (int f = 0; f < 16; ++f) We[f] = wp[f];
        #pragma unroll
        for (int p = 0; p < 2; ++p) {
            float a0 = 0.f, a1 = 0.f, a2 = 0.f, a3 = 0.f;
            #pragma unroll
            for (int f = 0; f < 16; ++f) {
                float xv = ((const float*)&xf[p][f >> 2])[f & 3];
                a0 += xv * We[f].x; a1 += xv * We[f].y;
                a2 += xv * We[f].z; a3 += xv * We[f].w;
            }
            float av4[4] = {a0, a1, a2, a3};
            int bcl = p * 4 + bclA;
            #pragma unroll
            for (int o = 0; o < 4; ++o) {
                int r = bcl * 4 + o;
                int byteoff = (((e * 32 + r) << 8) + (nn << 1)) ^ ((r & 7) << 4);
                *(unsigned short*)(smem + byteoff) = f2bf(av4[o]);
            }
        }
    }
    __syncthreads();

    // ================= gate on At =================
    if (t < 16) {
        while (__hip_atomic_load(&flags[t], __ATOMIC_ACQUIRE,
                                 __HIP_MEMORY_SCOPE_AGENT) != MAGIC)
            __builtin_amdgcn_s_sleep(1);
    }
    __threadfence();
    __syncthreads();

    // ================= phase 2: MFMA =================
    const int wid  = t >> 6;
    const int l    = t & 63;
    const int e    = wid >> 1;      // 0..3
    const int half = wid & 1;       // m-half
    const int lr   = l & 15;
    const int lg   = l >> 4;

    bf16x8 afrag[2][4];
    #pragma unroll
    for (int rt = 0; rt < 2; ++rt) {
        #pragma unroll
        for (int ks = 0; ks < 4; ++ks) {
            int row = rt * 16 + lr;
            int n0 = ks * 32 + lg * 8;
            int byteoff = (((e * 32 + row) << 8) + (n0 << 1)) ^ ((row & 7) << 4);
            afrag[rt][ks] = __builtin_bit_cast(bf16x8, *(const short8*)(smem + byteoff));
        }
    }

    floatx4 acc[2][4];
    #pragma unroll
    for (int rt = 0; rt < 2; ++rt)
        #pragma unroll
        for (int mt = 0; mt < 4; ++mt)
            acc[rt][mt] = (floatx4){0.f, 0.f, 0.f, 0.f};

    const unsigned short* Ate = At + (size_t)e * 16384;
    #pragma unroll
    for (int mt = 0; mt < 4; ++mt) {
        int m = half * 64 + mt * 16 + lr;
        bf16x8 bfrag[4];
        #pragma unroll
        for (int ks = 0; ks < 4; ++ks) {
            short8 v = *(const short8*)(Ate + (size_t)m * 128 + ks * 32 + lg * 8);
            bfrag[ks] = __builtin_bit_cast(bf16x8, v);
        }
        #pragma unroll
        for (int ks = 0; ks < 4; ++ks) {
            acc[0][mt] = __builtin_amdgcn_mfma_f32_16x16x32_bf16(
                afrag[0][ks], bfrag[ks], acc[0][mt], 0, 0, 0);
            acc[1][mt] = __builtin_amdgcn_mfma_f32_16x16x32_bf16(
                afrag[1][ks], bfrag[ks], acc[1][mt], 0, 0, 0);
        }
    }

    // epilogue: D col=lr (m), row = lg*4+j -> r = rt*16+lg*4+j -> bcl=rt*4+lg, o=j
    #pragma unroll
    for (int rt = 0; rt < 2; ++rt) {
        int bc = bc0 + rt * 4 + lg;
        int b = bc >> 4, c = bc & 15;
        float4* outp = (float4*)out + ((size_t)(b * 64 + e * 16 + c) * 128);
        #pragma unroll
        for (int mt = 0; mt < 4; ++mt) {
            int m = half * 64 + mt * 16 + lr;
            float4 o4;
            o4.x = fmaxf(acc[rt][mt][0], 0.f);
            o4.y = fmaxf(acc[rt][mt][1], 0.f);
            o4.z = fmaxf(acc[rt][mt][2], 0.f);
            o4.w = fmaxf(acc[rt][mt][3], 0.f);
            outp[m] = o4;
        }
    }
}

extern "C" void kernel_launch(void* const* d_in, const int* in_sizes, int n_in,
                              void* d_out, int out_size, void* d_ws, size_t ws_size,
                              hipStream_t stream) {
    const float* x = (const float*)d_in[0];   // [128,16,128,16]
    const float* A = (const float*)d_in[1];   // [4,128,128]
    const float* W = (const float*)d_in[2];   // [4,16,4]
    float* out = (float*)d_out;               // [128,64,128,4]
    unsigned short* At = (unsigned short*)d_ws;               // 128 KB
    unsigned* flags = (unsigned*)((char*)d_ws + 131072);      // 16 x u32

    hipMemsetAsync(flags, 0, 16 * sizeof(unsigned), stream);
    gcn_fused_kernel<<<256, 512, 0, stream>>>(x, A, W, At, flags, out);
}

// Round 4
// 23.335 us; speedup vs baseline: 2.5300x; 2.5300x over previous
//
#include <hip/hip_runtime.h>
#include <math.h>

#define EPSN 1e-12f

typedef __attribute__((ext_vector_type(8))) __bf16 bf16x8;
typedef __attribute__((ext_vector_type(8))) short short8;
typedef __attribute__((ext_vector_type(4))) float floatx4;

static __device__ __forceinline__ unsigned short f2bf(float f) {
    return __builtin_bit_cast(unsigned short, (__bf16)f);
}

// ---------------------------------------------------------------------------
// Prep: At[e][m][n] = bf16( A[e][n][m] / max(||A[e][:][m]||_2, eps) )
// grid = 16 blocks (e in 0..3, m-chunk of 32), 256 threads  [verified round 2]
// ---------------------------------------------------------------------------
__global__ __launch_bounds__(256)
void prep_kernel(const float* __restrict__ A, unsigned short* __restrict__ At) {
    __shared__ float Asub[128][33];   // [n][m_local], padded
    __shared__ float red[8][32];
    __shared__ float rnv[32];
    const int t  = threadIdx.x;
    const int e  = blockIdx.x >> 2;
    const int m0 = (blockIdx.x & 3) * 32;
    const float* Ae = A + e * 16384 + m0;

    #pragma unroll
    for (int i = 0; i < 16; ++i) {
        int idx = t + i * 256;            // 0..4095
        int n = idx >> 5, ml = idx & 31;
        Asub[n][ml] = Ae[n * 128 + ml];   // coalesced in m
    }
    __syncthreads();
    {
        int ml = t & 31, g = t >> 5;
        float s = 0.f;
        #pragma unroll
        for (int j = 0; j < 16; ++j) {
            float v = Asub[g * 16 + j][ml];
            s += v * v;
        }
        red[g][ml] = s;
    }
    __syncthreads();
    if (t < 32) {
        float s = 0.f;
        #pragma unroll
        for (int g = 0; g < 8; ++g) s += red[g][t];
        rnv[t] = 1.0f / fmaxf(sqrtf(s), EPSN);
    }
    __syncthreads();
    {
        int ml = t >> 3;
        int n0 = (t & 7) * 16;
        float r = rnv[ml];
        unsigned short hs[16];
        #pragma unroll
        for (int j = 0; j < 16; ++j)
            hs[j] = f2bf(Asub[n0 + j][ml] * r);
        uint4* dst = (uint4*)(At + ((size_t)(e * 128 + m0 + ml) * 128 + n0));
        dst[0] = *(const uint4*)&hs[0];
        dst[1] = *(const uint4*)&hs[8];
    }
}

// ---------------------------------------------------------------------------
// Main: grid 1024 = (m-half h = gid>>9) x (bc-group of 4 = gid&511).
// Phase 1: XW[e][r=(bcl,o)][n] = x@W -> LDS bf16 [4e][16r][128n], XOR-swizzled.
// Phase 2: wave e: out[r, m in h-half] = relu( XW_e . At_e^T ) via
//          mfma_f32_16x16x32_bf16; coalesced float4 stores.
// ---------------------------------------------------------------------------
__global__ __launch_bounds__(256, 4)
void gcn_mfma_kernel(const float* __restrict__ x, const float* __restrict__ W,
                     const unsigned short* __restrict__ At,
                     float* __restrict__ out) {
    __shared__ __align__(16) unsigned short xw[8192];  // 4e x 16r x 128n bf16, swizzled

    const int t   = threadIdx.x;
    const int gid = blockIdx.x;
    const int h   = gid >> 9;          // m-half: blocks g and g+512 share bc -> same XCD
    const int bc0 = (gid & 511) * 4;

    // ---- phase 1: each thread handles 2 (bc_local, n) pairs ----
    float4 xf[2][4];
    int bcl_[2], n_[2];
    #pragma unroll
    for (int p = 0; p < 2; ++p) {
        int pair = t + p * 256;           // 0..511
        int bcl = pair >> 7, n = pair & 127;
        bcl_[p] = bcl; n_[p] = n;
        const float4* xp = (const float4*)(x + ((size_t)(bc0 + bcl) * 128 + n) * 16);
        xf[p][0] = xp[0]; xf[p][1] = xp[1]; xf[p][2] = xp[2]; xf[p][3] = xp[3];
    }
    #pragma unroll 1
    for (int e = 0; e < 4; ++e) {
        float4 We[16];                    // wave-uniform -> scalar loads
        const float4* wp = (const float4*)(W + e * 64);
        #pragma unroll
        for (int f = 0; f < 16; ++f) We[f] = wp[f];
        #pragma unroll
        for (int p = 0; p < 2; ++p) {
            float a0 = 0.f, a1 = 0.f, a2 = 0.f, a3 = 0.f;
            #pragma unroll
            for (int f = 0; f < 16; ++f) {
                float xv = ((const float*)&xf[p][f >> 2])[f & 3];
                a0 += xv * We[f].x; a1 += xv * We[f].y;
                a2 += xv * We[f].z; a3 += xv * We[f].w;
            }
            float av[4] = {a0, a1, a2, a3};
            int n = n_[p];
            #pragma unroll
            for (int o = 0; o < 4; ++o) {
                int r = bcl_[p] * 4 + o;
                int byteoff = (((e * 16 + r) << 8) + (n << 1)) ^ ((r & 7) << 4);
                *(unsigned short*)((char*)xw + byteoff) = f2bf(av[o]);
            }
        }
    }
    __syncthreads();

    // ---- phase 2: wave = e; GEMM 16r x 64m (half h), K=128 ----
    const int e  = t >> 6;
    const int l  = t & 63;
    const int lr = l & 15;    // A row r / B col m-offset
    const int lg = l >> 4;    // k-group

    bf16x8 afrag[4];
    #pragma unroll
    for (int ks = 0; ks < 4; ++ks) {
        int n0 = ks * 32 + lg * 8;
        int byteoff = (((e * 16 + lr) << 8) + (n0 << 1)) ^ ((lr & 7) << 4);
        short8 v = *(const short8*)((const char*)xw + byteoff);
        afrag[ks] = __builtin_bit_cast(bf16x8, v);
    }

    floatx4 acc[4];
    #pragma unroll
    for (int mt = 0; mt < 4; ++mt) acc[mt] = (floatx4){0.f, 0.f, 0.f, 0.f};

    const unsigned short* Ate = At + (size_t)e * 16384 + (size_t)h * 64 * 128;
    bf16x8 bfrag[4][4];
    #pragma unroll
    for (int mt = 0; mt < 4; ++mt) {
        int m = mt * 16 + lr;
        #pragma unroll
        for (int ks = 0; ks < 4; ++ks) {
            short8 v = *(const short8*)(Ate + (size_t)m * 128 + ks * 32 + lg * 8);
            bfrag[mt][ks] = __builtin_bit_cast(bf16x8, v);
        }
    }
    #pragma unroll
    for (int mt = 0; mt < 4; ++mt)
        #pragma unroll
        for (int ks = 0; ks < 4; ++ks)
            acc[mt] = __builtin_amdgcn_mfma_f32_16x16x32_bf16(
                afrag[ks], bfrag[mt][ks], acc[mt], 0, 0, 0);

    // ---- epilogue: D col = lr = m-offset; row = lg*4 + j -> bcl=lg, o=j
    const int bc = bc0 + lg, b = bc >> 4, c = bc & 15;
    float4* outp = (float4*)out + ((size_t)(b * 64 + e * 16 + c) * 128) + h * 64;
    #pragma unroll
    for (int mt = 0; mt < 4; ++mt) {
        int m = mt * 16 + lr;
        float4 o4;
        o4.x = fmaxf(acc[mt][0], 0.f);
        o4.y = fmaxf(acc[mt][1], 0.f);
        o4.z = fmaxf(acc[mt][2], 0.f);
        o4.w = fmaxf(acc[mt][3], 0.f);
        outp[m] = o4;
    }
}

extern "C" void kernel_launch(void* const* d_in, const int* in_sizes, int n_in,
                              void* d_out, int out_size, void* d_ws, size_t ws_size,
                              hipStream_t stream) {
    const float* x = (const float*)d_in[0];   // [128,16,128,16]
    const float* A = (const float*)d_in[1];   // [4,128,128]
    const float* W = (const float*)d_in[2];   // [4,16,4]
    float* out = (float*)d_out;               // [128,64,128,4]
    unsigned short* At = (unsigned short*)d_ws;  // 4*128*128 bf16 = 128 KB

    prep_kernel<<<16, 256, 0, stream>>>(A, At);
    gcn_mfma_kernel<<<1024, 256, 0, stream>>>(x, W, At, out);
}